// Round 9
// baseline (383.322 us; speedup 1.0000x reference)
//
#include <hip/hip_runtime.h>

#define BATCH   256
#define NFEAT   20000
#define NVEC    (NFEAT / 4)
#define KSEL    256
#define NSAMP   8
#define CAP     2048
#define SEL_REPS 10
#define WR_REPS  12

typedef unsigned long long u64;
typedef float __attribute__((ext_vector_type(4))) f32x4;

// Map float bits to unsigned key with same total order as float compare.
__device__ __forceinline__ unsigned fmap(float f) {
    unsigned u = __float_as_uint(f);
    return (u & 0x80000000u) ? ~u : (u | 0x80000000u);
}

// Generic top-down bin pick by wave 0 (rare refine path only).
__device__ __forceinline__ void select_bin_wave0(const unsigned* hist, int nbins, int w,
                                                 int* s_d, int* s_w, int lane) {
    for (int base = nbins - 1; base >= 0; base -= 64) {
        int bin = base - lane;
        unsigned c = (bin >= 0) ? hist[bin] : 0u;
        unsigned p = c;
#pragma unroll
        for (int off = 1; off < 64; off <<= 1) {
            unsigned t = __shfl_up(p, off);
            if (lane >= off) p += t;
        }
        unsigned long long m = __ballot(p >= (unsigned)w);
        if (m) {
            int l = __ffsll(m) - 1;
            if (lane == l) { *s_d = bin; *s_w = w - (int)(p - c); }
            return;
        }
        w -= (int)__shfl(p, 63);
    }
    if (lane == 0) { *s_d = 0; *s_w = 1; }
}

// Fast pick over exactly 64 entries (arr[63] = highest bin), wave 0 only.
__device__ __forceinline__ void pick64(const unsigned* arr, int w, int lane,
                                       int* s_idx, int* s_w) {
    unsigned c = arr[63 - lane];
    unsigned p = c;
#pragma unroll
    for (int off = 1; off < 64; off <<= 1) {
        unsigned t = __shfl_up(p, off);
        if (lane >= off) p += t;
    }
    unsigned long long m = __ballot(p >= (unsigned)w);
    if (m) {
        int l = __ffsll(m) - 1;
        if (lane == l) { *s_idx = 63 - l; *s_w = w - (int)(p - c); }
    } else if (lane == 0) { *s_idx = 0; *s_w = 1; }
}

// DIAGNOSTIC build: body repeated `reps` times (identical work & results each
// rep) so this dispatch exceeds the harness fills and lands in the top-5 with
// its own counters. Per-iteration cost = dur / reps.
__global__ __launch_bounds__(1024) void topk_select(const float* __restrict__ logits,
                                                    u64* __restrict__ rowthr, int reps) {
    const int b = blockIdx.x, tid = threadIdx.x;
    const int lane = tid & 63, wave = tid >> 6;
    const float4* __restrict__ row4 = (const float4*)(logits + (size_t)b * NFEAT);

    __shared__ unsigned hist[4096];     // 16 KB
    __shared__ u64 cand[CAP];           // 16 KB
    __shared__ unsigned csum[64];
    __shared__ int s_d, s_w;
    __shared__ unsigned s_cnt;
    __shared__ u64 s_thr;
    __shared__ int s_run, s_cut, s_wc[16];

    int zero = 0;                        // opaque 0: defeats hoist/CSE across reps
#pragma unroll 1
    for (int r = 0; r < reps; ++r) {
        asm volatile("" : "+v"(zero));

        // ---- Phase 1: loads + histogram ----
        float4 v[5];
#pragma unroll
        for (int j = 0; j < 5; ++j) {
            const int i4 = tid + j * 1024 + zero;
            v[j] = row4[(i4 < NVEC) ? i4 : (NVEC - 1)];
        }
#pragma unroll
        for (int j = 0; j < 4; ++j) hist[tid + j * 1024] = 0;
        __syncthreads();

        unsigned kk[5][4];
#pragma unroll
        for (int j = 0; j < 5; ++j) {
            kk[j][0] = fmap(v[j].x); kk[j][1] = fmap(v[j].y);
            kk[j][2] = fmap(v[j].z); kk[j][3] = fmap(v[j].w);
        }
#pragma unroll
        for (int j = 0; j < 4; ++j) {
#pragma unroll
            for (int e = 0; e < 4; ++e) atomicAdd(&hist[kk[j][e] >> 20], 1u);
        }
        if (tid + 4096 < NVEC) {
#pragma unroll
            for (int e = 0; e < 4; ++e) atomicAdd(&hist[kk[4][e] >> 20], 1u);
        }
        __syncthreads();

        // ---- Phase 2: hierarchical threshold-bin pick ----
        unsigned keypref; int w;
        {
#pragma unroll
            for (int j = 0; j < 4; ++j) {
                const int c = wave * 4 + j;
                unsigned x = hist[c * 64 + lane];
#pragma unroll
                for (int off = 32; off; off >>= 1) x += __shfl_down(x, off);
                if (lane == 0) csum[c] = x;
            }
            __syncthreads();
            if (wave == 0) pick64(csum, KSEL, lane, &s_d, &s_w);
            __syncthreads();
            const int chunk = s_d; const int w0 = s_w;
            if (wave == 0) pick64(&hist[chunk * 64], w0, lane, &s_d, &s_w);
            if (tid == 0) s_cnt = 0;
            __syncthreads();
            keypref = (unsigned)(chunk * 64 + s_d);
            w = s_w;
        }
        int shift = 20;

        // ---- Phase 3: gather candidate composites from registers ----
        unsigned C;
        for (;;) {
#pragma unroll
            for (int j = 0; j < 5; ++j) {
                const int i4 = tid + j * 1024;
                if (i4 < NVEC) {
#pragma unroll
                    for (int e = 0; e < 4; ++e) {
                        const unsigned k = kk[j][e];
                        if ((k >> shift) == keypref) {
                            unsigned p = atomicAdd(&s_cnt, 1u);
                            if (p < CAP) cand[p] = ((u64)k << 32) | (unsigned)~(4 * i4 + e);
                        }
                    }
                }
            }
            __syncthreads();
            C = s_cnt;
            if (C <= CAP || shift == 0) break;

            const int nb = (shift >= 12) ? 12 : shift;
            const int nsh = shift - nb;
            for (int i = tid; i < (1 << nb); i += 1024) hist[i] = 0;
            __syncthreads();
#pragma unroll
            for (int j = 0; j < 5; ++j) {
                const int i4 = tid + j * 1024;
                if (i4 < NVEC) {
#pragma unroll
                    for (int e = 0; e < 4; ++e) {
                        const unsigned k = kk[j][e];
                        if ((k >> shift) == keypref)
                            atomicAdd(&hist[(k >> nsh) & ((1u << nb) - 1u)], 1u);
                    }
                }
            }
            __syncthreads();
            if (wave == 0) select_bin_wave0(hist, 1 << nb, w, &s_d, &s_w, lane);
            if (tid == 0) s_cnt = 0;
            __syncthreads();
            keypref = (keypref << nb) | (unsigned)s_d;
            w = s_w;
            shift = nsh;
        }

        // ---- Phase 4: resolve exact threshold ----
        if (C <= CAP) {
            for (int i = tid; i < (int)C; i += 1024) {
                const u64 ci = cand[i];
                int cgt = 0;
                for (int j = 0; j < (int)C; ++j) cgt += (cand[j] > ci) ? 1 : 0;
                if (cgt == w - 1) s_thr = ci;
            }
            __syncthreads();
        } else {
            if (tid == 0) { s_run = 0; s_cut = 0; }
            __syncthreads();
#pragma unroll 1
            for (int j = 0; j < 5; ++j) {
                const int i4 = tid + j * 1024;
                bool eq[4];
                int cnt4 = 0;
#pragma unroll
                for (int e = 0; e < 4; ++e) {
                    eq[e] = (i4 < NVEC) && (kk[j][e] == keypref);
                    cnt4 += eq[e] ? 1 : 0;
                }
                unsigned p = (unsigned)cnt4;
#pragma unroll
                for (int off = 1; off < 64; off <<= 1) {
                    unsigned t = __shfl_up(p, off);
                    if (lane >= off) p += t;
                }
                const unsigned excl = p - (unsigned)cnt4;
                if (lane == 63) s_wc[wave] = (int)p;
                __syncthreads();
                int off0 = s_run + (int)excl;
                for (int x = 0; x < wave; ++x) off0 += s_wc[x];
#pragma unroll
                for (int e = 0; e < 4; ++e) {
                    if (eq[e]) { if (off0 == w - 1) s_cut = 4 * i4 + e; ++off0; }
                }
                __syncthreads();
                if (tid == 0) { int t = 0; for (int x = 0; x < 16; ++x) t += s_wc[x]; s_run += t; }
                __syncthreads();
                if (s_run >= w) break;
            }
            if (tid == 0) s_thr = ((u64)keypref << 32) | (unsigned)~s_cut;
            __syncthreads();
        }

        if (tid == 0) rowthr[b] = s_thr;
        __syncthreads();
        asm volatile("" ::: "memory");   // stores/loads must not merge across reps
    }
}

// DIAGNOSTIC build: body repeated `reps` times; every rep writes the identical
// mask, so the final output is exactly correct. Per-iteration cost = dur / reps.
__global__ __launch_bounds__(256) void write_out(const float* __restrict__ logits,
                                                 const u64* __restrict__ rowthr,
                                                 float* __restrict__ out, int reps) {
    const int b = blockIdx.y;
    const int q = blockIdx.x * 256 + threadIdx.x;   // index over N/4
    if (q >= NVEC) return;

    int zero = 0;
#pragma unroll 1
    for (int r = 0; r < reps; ++r) {
        asm volatile("" : "+v"(zero));
        const u64 thr = rowthr[b + zero];
        const unsigned thr_k = (unsigned)(thr >> 32);
        const unsigned thr_l = (unsigned)thr;
        const int n = q * 4;
        const float4 v = *reinterpret_cast<const float4*>(logits + (size_t)(b + zero) * NFEAT + n);

        f32x4 m;
        {
            const float* vf = &v.x;
#pragma unroll
            for (int j = 0; j < 4; ++j) {
                const unsigned k = fmap(vf[j]);
                const bool sel = (k > thr_k) || (k == thr_k && (unsigned)~(n + j) >= thr_l);
                m[j] = sel ? 1.0f : 0.0f;
            }
        }

#pragma unroll
        for (int s = 0; s < NSAMP; ++s) {
            *reinterpret_cast<f32x4*>(out + ((size_t)s * BATCH + b) * NFEAT + n) = m;
        }
        asm volatile("" ::: "memory");
    }
}

extern "C" void kernel_launch(void* const* d_in, const int* in_sizes, int n_in,
                              void* d_out, int out_size, void* d_ws, size_t ws_size,
                              hipStream_t stream) {
    const float* logits = (const float*)d_in[0];
    float* out = (float*)d_out;
    u64* rowthr = (u64*)d_ws;   // 256 * 8 B = 2 KB

    topk_select<<<BATCH, 1024, 0, stream>>>(logits, rowthr, SEL_REPS);

    dim3 grid((NVEC + 255) / 256, BATCH);
    write_out<<<grid, 256, 0, stream>>>(logits, rowthr, out, WR_REPS);
}

// Round 10
// 36.474 us; speedup vs baseline: 10.5094x; 10.5094x over previous
//
#include <hip/hip_runtime.h>

#define BATCH   256
#define NFEAT   20000
#define NVEC    (NFEAT / 4)
#define KSEL    256
#define NSAMP   8
#define CAP     2048

typedef unsigned long long u64;
typedef float __attribute__((ext_vector_type(4))) f32x4;

// Raw barrier: orders LDS (lgkmcnt) but does NOT drain vmcnt — zero-stores
// stay in flight across select-phase barriers. All cross-wave communication
// in this kernel is LDS-only, so lgkmcnt(0) + s_barrier is sufficient.
#define BAR() do { asm volatile("s_waitcnt lgkmcnt(0)" ::: "memory"); \
                   __builtin_amdgcn_s_barrier();                      \
                   asm volatile("" ::: "memory"); } while (0)

// Map float bits to unsigned key with same total order as float compare.
__device__ __forceinline__ unsigned fmap(float f) {
    unsigned u = __float_as_uint(f);
    return (u & 0x80000000u) ? ~u : (u | 0x80000000u);
}

// Generic top-down bin pick by wave 0 (rare refine path only).
__device__ __forceinline__ void select_bin_wave0(const unsigned* hist, int nbins, int w,
                                                 int* s_d, int* s_w, int lane) {
    for (int base = nbins - 1; base >= 0; base -= 64) {
        int bin = base - lane;
        unsigned c = (bin >= 0) ? hist[bin] : 0u;
        unsigned p = c;
#pragma unroll
        for (int off = 1; off < 64; off <<= 1) {
            unsigned t = __shfl_up(p, off);
            if (lane >= off) p += t;
        }
        unsigned long long m = __ballot(p >= (unsigned)w);
        if (m) {
            int l = __ffsll(m) - 1;
            if (lane == l) { *s_d = bin; *s_w = w - (int)(p - c); }
            return;
        }
        w -= (int)__shfl(p, 63);
    }
    if (lane == 0) { *s_d = 0; *s_w = 1; }
}

// Fast pick over exactly 64 entries (arr[63] = highest bin), wave 0 only.
__device__ __forceinline__ void pick64(const unsigned* arr, int w, int lane,
                                       int* s_idx, int* s_w) {
    unsigned c = arr[63 - lane];
    unsigned p = c;
#pragma unroll
    for (int off = 1; off < 64; off <<= 1) {
        unsigned t = __shfl_up(p, off);
        if (lane >= off) p += t;
    }
    unsigned long long m = __ballot(p >= (unsigned)w);
    if (m) {
        int l = __ffsll(m) - 1;
        if (lane == l) { *s_idx = 63 - l; *s_w = w - (int)(p - c); }
    } else if (lane == 0) { *s_idx = 0; *s_w = 1; }
}

// One 1024-thread block per row; row held in registers (20 keys/thread).
// Zero-stores for the entire output row (all 8 slices) are ISSUED during the
// select phases and drain at cache/HBM rate while the select runs; after the
// exact top-K threshold (64-bit composite key<<32 | ~idx, tie-break = lowest
// index = jax.lax.top_k) is known, vmcnt(0) + each thread rewrites its own
// selected elements with 1.0 (same-thread same-address => ordered).
__global__ __launch_bounds__(1024) void topk_fused(const float* __restrict__ logits,
                                                   float* __restrict__ out) {
    const int b = blockIdx.x, tid = threadIdx.x;
    const int lane = tid & 63, wave = tid >> 6;
    const float4* __restrict__ row4 = (const float4*)(logits + (size_t)b * NFEAT);
    const size_t BN = (size_t)BATCH * NFEAT;
    float* const outb = out + (size_t)b * NFEAT;
    const f32x4 z4 = {0.0f, 0.0f, 0.0f, 0.0f};

#define ZSTORE(J)                                                              \
    do {                                                                       \
        const int i4_ = tid + (J) * 1024;                                      \
        if (i4_ < NVEC) {                                                      \
            _Pragma("unroll")                                                  \
            for (int s_ = 0; s_ < NSAMP; ++s_)                                 \
                *reinterpret_cast<f32x4*>(outb + (size_t)s_ * BN + 4 * i4_) = z4; \
        }                                                                      \
    } while (0)

    __shared__ unsigned hist[4096];     // 16 KB
    __shared__ u64 cand[CAP];           // 16 KB
    __shared__ unsigned csum[64];
    __shared__ int s_d, s_w;
    __shared__ unsigned s_cnt;
    __shared__ u64 s_thr;
    __shared__ int s_run, s_cut, s_wc[16];

    // ---- Phase 1: issue row loads, then zero-stores chunks 0-1 ----
    float4 v[5];
#pragma unroll
    for (int j = 0; j < 5; ++j) {
        const int i4 = tid + j * 1024;
        v[j] = row4[(i4 < NVEC) ? i4 : (NVEC - 1)];
    }
    ZSTORE(0);
    ZSTORE(1);
#pragma unroll
    for (int j = 0; j < 4; ++j) hist[tid + j * 1024] = 0;
    BAR();

    unsigned kk[5][4];
#pragma unroll
    for (int j = 0; j < 5; ++j) {
        kk[j][0] = fmap(v[j].x); kk[j][1] = fmap(v[j].y);
        kk[j][2] = fmap(v[j].z); kk[j][3] = fmap(v[j].w);
    }
#pragma unroll
    for (int j = 0; j < 4; ++j) {
#pragma unroll
        for (int e = 0; e < 4; ++e) atomicAdd(&hist[kk[j][e] >> 20], 1u);
    }
    if (tid + 4096 < NVEC) {
#pragma unroll
        for (int e = 0; e < 4; ++e) atomicAdd(&hist[kk[4][e] >> 20], 1u);
    }
    ZSTORE(2);
    BAR();

    // ---- Phase 2: hierarchical threshold-bin pick ----
    unsigned keypref; int w;
    {
#pragma unroll
        for (int j = 0; j < 4; ++j) {
            const int cc = wave * 4 + j;
            unsigned x = hist[cc * 64 + lane];
#pragma unroll
            for (int off = 32; off; off >>= 1) x += __shfl_down(x, off);
            if (lane == 0) csum[cc] = x;
        }
        BAR();
        if (wave == 0) pick64(csum, KSEL, lane, &s_d, &s_w);
        BAR();
        const int chunk = s_d; const int w0 = s_w;
        if (wave == 0) pick64(&hist[chunk * 64], w0, lane, &s_d, &s_w);
        if (tid == 0) s_cnt = 0;
        BAR();
        keypref = (unsigned)(chunk * 64 + s_d);
        w = s_w;
    }
    int shift = 20;
    ZSTORE(3);

    // ---- Phase 3: gather candidate composites from registers ----
    unsigned C;
    for (;;) {
#pragma unroll
        for (int j = 0; j < 5; ++j) {
            const int i4 = tid + j * 1024;
            if (i4 < NVEC) {
#pragma unroll
                for (int e = 0; e < 4; ++e) {
                    const unsigned k = kk[j][e];
                    if ((k >> shift) == keypref) {
                        unsigned p = atomicAdd(&s_cnt, 1u);
                        if (p < CAP) cand[p] = ((u64)k << 32) | (unsigned)~(4 * i4 + e);
                    }
                }
            }
        }
        BAR();
        C = s_cnt;
        if (C <= CAP || shift == 0) break;

        // rare: refine key prefix from reg keys until candidate set fits
        const int nb = (shift >= 12) ? 12 : shift;
        const int nsh = shift - nb;
        for (int i = tid; i < (1 << nb); i += 1024) hist[i] = 0;
        BAR();
#pragma unroll
        for (int j = 0; j < 5; ++j) {
            const int i4 = tid + j * 1024;
            if (i4 < NVEC) {
#pragma unroll
                for (int e = 0; e < 4; ++e) {
                    const unsigned k = kk[j][e];
                    if ((k >> shift) == keypref)
                        atomicAdd(&hist[(k >> nsh) & ((1u << nb) - 1u)], 1u);
                }
            }
        }
        BAR();
        if (wave == 0) select_bin_wave0(hist, 1 << nb, w, &s_d, &s_w, lane);
        if (tid == 0) s_cnt = 0;
        BAR();
        keypref = (keypref << nb) | (unsigned)s_d;
        w = s_w;
        shift = nsh;
    }
    ZSTORE(4);

    // ---- Phase 4: resolve exact threshold (12-bit radix refine, all waves) ----
    if (C <= CAP) {
        u64 pfx = keypref;          // candidates share composite>>pshift == pfx
        int pshift = 32 + shift;    // = 52 on the common path
        bool done = false;
        while (!done) {
            const int nb = (pshift >= 12) ? 12 : pshift;
            const int nsh = pshift - nb;
            const int nbins = 1 << nb;
            for (int i = tid; i < nbins; i += 1024) hist[i] = 0;
            BAR();
            for (int i = tid; i < (int)C; i += 1024) {
                const u64 cd = cand[i];
                if ((cd >> pshift) == pfx)
                    atomicAdd(&hist[(unsigned)(cd >> nsh) & (unsigned)(nbins - 1)], 1u);
            }
            BAR();
            unsigned d;
            if (nb == 12) {
                // hierarchical pick over 4096 bins (all 16 waves + 2x pick64)
#pragma unroll
                for (int j = 0; j < 4; ++j) {
                    const int cc = wave * 4 + j;
                    unsigned x = hist[cc * 64 + lane];
#pragma unroll
                    for (int off = 32; off; off >>= 1) x += __shfl_down(x, off);
                    if (lane == 0) csum[cc] = x;
                }
                BAR();
                if (wave == 0) pick64(csum, w, lane, &s_d, &s_w);
                BAR();
                const int chunk = s_d; const int w0 = s_w;
                if (wave == 0) pick64(&hist[chunk * 64], w0, lane, &s_d, &s_w);
                BAR();
                d = (unsigned)(chunk * 64 + s_d);
            } else {
                if (wave == 0) select_bin_wave0(hist, nbins, w, &s_d, &s_w, lane);
                BAR();
                d = (unsigned)s_d;
            }
            w = s_w;
            const unsigned cnt = hist[d];
            pfx = (pfx << nb) | d;
            pshift = nsh;
            if (cnt == 1u || pshift == 0) {
                if (cnt == 1u && pshift > 0) {
                    // unique candidate with this prefix IS the threshold
                    for (int i = tid; i < (int)C; i += 1024) {
                        const u64 cd = cand[i];
                        if ((cd >> pshift) == pfx) s_thr = cd;   // exactly one writer
                    }
                } else if (tid == 0) {
                    s_thr = pfx;   // fully resolved composite
                }
                done = true;
            }
            BAR();
        }
    } else {
        // unreachable in practice: shift==0 with >CAP exact-duplicate keys.
        if (tid == 0) { s_run = 0; s_cut = 0; }
        BAR();
#pragma unroll 1
        for (int j = 0; j < 5; ++j) {
            const int i4 = tid + j * 1024;
            bool eq[4];
            int cnt4 = 0;
#pragma unroll
            for (int e = 0; e < 4; ++e) {
                eq[e] = (i4 < NVEC) && (kk[j][e] == keypref);
                cnt4 += eq[e] ? 1 : 0;
            }
            unsigned p = (unsigned)cnt4;
#pragma unroll
            for (int off = 1; off < 64; off <<= 1) {
                unsigned t = __shfl_up(p, off);
                if (lane >= off) p += t;
            }
            const unsigned excl = p - (unsigned)cnt4;
            if (lane == 63) s_wc[wave] = (int)p;
            BAR();
            int off0 = s_run + (int)excl;
            for (int x = 0; x < wave; ++x) off0 += s_wc[x];
#pragma unroll
            for (int e = 0; e < 4; ++e) {
                if (eq[e]) { if (off0 == w - 1) s_cut = 4 * i4 + e; ++off0; }
            }
            BAR();
            if (tid == 0) { int t = 0; for (int x = 0; x < 16; ++x) t += s_wc[x]; s_run += t; }
            BAR();
            if (s_run >= w) break;
        }
        if (tid == 0) s_thr = ((u64)keypref << 32) | (unsigned)~s_cut;
        BAR();
    }

    // ---- Phase 5: drain zero-stores, then rewrite own selected elems = 1.0 ----
    const u64 thr = s_thr;
    const unsigned thr_k = (unsigned)(thr >> 32);
    const unsigned thr_l = (unsigned)thr;
    asm volatile("s_waitcnt vmcnt(0)" ::: "memory");
#pragma unroll
    for (int j = 0; j < 5; ++j) {
        const int i4 = tid + j * 1024;
        if (i4 < NVEC) {
            const int n = 4 * i4;
#pragma unroll
            for (int e = 0; e < 4; ++e) {
                const unsigned k = kk[j][e];
                const bool sel = (k > thr_k) || (k == thr_k && (unsigned)~(n + e) >= thr_l);
                if (sel) {
#pragma unroll
                    for (int s = 0; s < NSAMP; ++s)
                        outb[(size_t)s * BN + n + e] = 1.0f;
                }
            }
        }
    }
#undef ZSTORE
}

extern "C" void kernel_launch(void* const* d_in, const int* in_sizes, int n_in,
                              void* d_out, int out_size, void* d_ws, size_t ws_size,
                              hipStream_t stream) {
    const float* logits = (const float*)d_in[0];
    float* out = (float*)d_out;
    (void)d_ws; (void)ws_size;

    topk_fused<<<BATCH, 1024, 0, stream>>>(logits, out);
}